// Round 11
// baseline (129.529 us; speedup 1.0000x reference)
//
#include <hip/hip_runtime.h>
#include <hip/hip_bf16.h>
#include <math.h>

#define IN_CH 512
#define HID   1024
#define NH    16
#define HD    64
#define BSZ   1024
#define KVB   2064
#define NPAD  2112
#define LN_EPS 1e-5f

typedef _Float16 f16x8 __attribute__((ext_vector_type(8)));
typedef float f32x4  __attribute__((ext_vector_type(4)));
typedef unsigned short u16;

__device__ inline void split16(float f, u16& hi, u16& lo) {
    _Float16 h = (_Float16)f;
    _Float16 l = (_Float16)(f - (float)h);
    hi = __builtin_bit_cast(u16, h);
    lo = __builtin_bit_cast(u16, l);
}
__device__ inline u16 f2h(float f) {
    _Float16 h = (_Float16)f;
    return __builtin_bit_cast(u16, h);
}

__device__ inline void gload16(const void* g, void* l) {
    __builtin_amdgcn_global_load_lds(
        (const __attribute__((address_space(1))) unsigned int*)g,
        (__attribute__((address_space(3))) unsigned int*)l, 16, 0, 0);
}

#define QX (BSZ * IN_CH / 4)              // 131072
#define QW (HID * IN_CH / 4)              // 131072
#define QK (NPAD * HID / 4)               // 540672
#define QKVALID (KVB * HID / 4)           // 528384

// ------------- D1: x -> (xh,xl) fp16 split; w_in -> fp16 ----------------------
__global__ __launch_bounds__(256) void cvt_xw(const float* __restrict__ x,
                                              const float* __restrict__ w_in,
                                              u16* __restrict__ xh, u16* __restrict__ xl,
                                              u16* __restrict__ wih) {
    long q = (long)blockIdx.x * 256 + threadIdx.x;
    if (q < QX) {
        float4 v = ((const float4*)x)[q];
        float f[4] = {v.x, v.y, v.z, v.w};
        ushort4 hh4, ll4;
        u16 hb[4], lb[4];
        #pragma unroll
        for (int j = 0; j < 4; ++j) split16(f[j], hb[j], lb[j]);
        hh4.x = hb[0]; hh4.y = hb[1]; hh4.z = hb[2]; hh4.w = hb[3];
        ll4.x = lb[0]; ll4.y = lb[1]; ll4.z = lb[2]; ll4.w = lb[3];
        ((ushort4*)xh)[q] = hh4;
        ((ushort4*)xl)[q] = ll4;
    } else {
        long lq = q - QX;
        float4 v = ((const float4*)w_in)[lq];
        ushort4 hh4;
        hh4.x = f2h(v.x); hh4.y = f2h(v.y); hh4.z = f2h(v.z); hh4.w = f2h(v.w);
        ((ushort4*)wih)[lq] = hh4;
    }
}

// ------------- D2: gemm1 (fp16, A split 2-term, BK=64, XOR swizzle) -----------
template<int BM, int BN, int KK>
__global__ __launch_bounds__(256) void gemm_f16s(const u16* __restrict__ Ah_g,
                                                 const u16* __restrict__ Al_g,
                                                 const u16* __restrict__ Bh_g,
                                                 const float* __restrict__ bias,
                                                 float* __restrict__ C,
                                                 int N, int ldc) {
    constexpr int WM = BM / 2, WN = BN / 2, MF = WM / 16, NF = WN / 16;
    constexpr int UA = BM / 8;
    constexpr int U  = 2 * UA + BN / 8;
    __shared__ __align__(16) u16 Ah[2][BM][64];
    __shared__ __align__(16) u16 Al[2][BM][64];
    __shared__ __align__(16) u16 Bh[2][BN][64];

    const int t = threadIdx.x, lane = t & 63, wid = t >> 6;
    const int wm = wid >> 1, wn = wid & 1;
    const int m0 = blockIdx.y * BM, n0 = blockIdx.x * BN;

    const int seg = (lane & 7) ^ (lane >> 3);
    const int r8  = lane >> 3;

    f32x4 acc[MF][NF] = {};

    auto stage = [&](int buf, int k0) {
        #pragma unroll
        for (int it = 0; it < U / 4; ++it) {
            int u = it * 4 + wid;
            if (u < UA) {
                int row = u * 8 + r8;
                gload16(Ah_g + (size_t)(m0 + row) * KK + k0 + seg * 8,
                        &Ah[buf][u * 8][0]);
            } else if (u < 2 * UA) {
                int uu = u - UA;
                int row = uu * 8 + r8;
                gload16(Al_g + (size_t)(m0 + row) * KK + k0 + seg * 8,
                        &Al[buf][uu * 8][0]);
            } else {
                int bu = u - 2 * UA;
                int row = bu * 8 + r8;
                gload16(Bh_g + (size_t)(n0 + row) * KK + k0 + seg * 8,
                        &Bh[buf][bu * 8][0]);
            }
        }
    };

    constexpr int KT = KK / 64;
    stage(0, 0);
    __syncthreads();
    int buf = 0;
    for (int kt = 0; kt < KT; ++kt) {
        if (kt + 1 < KT) stage(buf ^ 1, (kt + 1) * 64);

        f16x8 ah[2][MF], al[2][MF], bh[2][NF];
        #pragma unroll
        for (int s = 0; s < 2; ++s) {
            #pragma unroll
            for (int mf = 0; mf < MF; ++mf) {
                int r = wm * WM + mf * 16 + (lane & 15);
                int pc = ((s << 2) | (lane >> 4)) ^ (r & 7);
                ah[s][mf] = *(const f16x8*)&Ah[buf][r][pc * 8];
                al[s][mf] = *(const f16x8*)&Al[buf][r][pc * 8];
            }
            #pragma unroll
            for (int nf = 0; nf < NF; ++nf) {
                int r = wn * WN + nf * 16 + (lane & 15);
                int pc = ((s << 2) | (lane >> 4)) ^ (r & 7);
                bh[s][nf] = *(const f16x8*)&Bh[buf][r][pc * 8];
            }
        }
        #pragma unroll
        for (int s = 0; s < 2; ++s)
            #pragma unroll
            for (int mf = 0; mf < MF; ++mf)
                #pragma unroll
                for (int nf = 0; nf < NF; ++nf) {
                    acc[mf][nf] = __builtin_amdgcn_mfma_f32_16x16x32_f16(ah[s][mf], bh[s][nf], acc[mf][nf], 0, 0, 0);
                    acc[mf][nf] = __builtin_amdgcn_mfma_f32_16x16x32_f16(al[s][mf], bh[s][nf], acc[mf][nf], 0, 0, 0);
                }
        __syncthreads();
        buf ^= 1;
    }

    #pragma unroll
    for (int mf = 0; mf < MF; ++mf)
        #pragma unroll
        for (int nf = 0; nf < NF; ++nf) {
            int col = n0 + wn * WN + nf * 16 + (lane & 15);
            if (col < N) {
                float bb = bias[col];
                #pragma unroll
                for (int r = 0; r < 4; ++r) {
                    int row = m0 + wm * WM + mf * 16 + ((lane >> 4) << 2) + r;
                    C[(size_t)row * ldc + col] = acc[mf][nf][r] + bb;
                }
            }
        }
}

// ------------- D4: gemm2 (pure single fp16, BK=64, XOR swizzle, XCD remap) ----
template<int BM, int BN, int KK>
__global__ __launch_bounds__(256) void gemm_f16x(const u16* __restrict__ Ah_g,
                                                 const u16* __restrict__ Bh_g,
                                                 const float* __restrict__ bias,
                                                 float* __restrict__ C,
                                                 int N, int ldc) {
    constexpr int WM = BM / 2, WN = BN / 2, MF = WM / 16, NF = WN / 16;
    constexpr int UA = BM / 8;
    constexpr int U  = UA + BN / 8;
    __shared__ __align__(16) u16 Ah[2][BM][64];
    __shared__ __align__(16) u16 Bh[2][BN][64];

    const int t = threadIdx.x, lane = t & 63, wid = t >> 6;
    const int wm = wid >> 1, wn = wid & 1;

    // XCD-chunked bijective remap (grid % 8 == 0)
    const int bid = blockIdx.x, nwg = gridDim.x;
    const int w = (bid & 7) * (nwg >> 3) + (bid >> 3);
    const int mt = w & (BSZ / BM - 1);
    const int nt = w / (BSZ / BM);
    const int m0 = mt * BM, n0 = nt * BN;

    const int seg = (lane & 7) ^ (lane >> 3);
    const int r8  = lane >> 3;

    f32x4 acc[MF][NF] = {};

    auto stage = [&](int buf, int k0) {
        #pragma unroll
        for (int it = 0; it < U / 4; ++it) {
            int u = it * 4 + wid;
            if (u < UA) {
                int row = u * 8 + r8;
                gload16(Ah_g + (size_t)(m0 + row) * KK + k0 + seg * 8,
                        &Ah[buf][u * 8][0]);
            } else {
                int bu = u - UA;
                int row = bu * 8 + r8;
                gload16(Bh_g + (size_t)(n0 + row) * KK + k0 + seg * 8,
                        &Bh[buf][bu * 8][0]);
            }
        }
    };

    constexpr int KT = KK / 64;
    stage(0, 0);
    __syncthreads();
    int buf = 0;
    for (int kt = 0; kt < KT; ++kt) {
        if (kt + 1 < KT) stage(buf ^ 1, (kt + 1) * 64);

        f16x8 ah[2][MF], bh[2][NF];
        #pragma unroll
        for (int s = 0; s < 2; ++s) {
            #pragma unroll
            for (int mf = 0; mf < MF; ++mf) {
                int r = wm * WM + mf * 16 + (lane & 15);
                int pc = ((s << 2) | (lane >> 4)) ^ (r & 7);
                ah[s][mf] = *(const f16x8*)&Ah[buf][r][pc * 8];
            }
            #pragma unroll
            for (int nf = 0; nf < NF; ++nf) {
                int r = wn * WN + nf * 16 + (lane & 15);
                int pc = ((s << 2) | (lane >> 4)) ^ (r & 7);
                bh[s][nf] = *(const f16x8*)&Bh[buf][r][pc * 8];
            }
        }
        #pragma unroll
        for (int s = 0; s < 2; ++s)
            #pragma unroll
            for (int mf = 0; mf < 2; ++mf)
                #pragma unroll
                for (int nf = 0; nf < NF; ++nf)
                    acc[mf][nf] = __builtin_amdgcn_mfma_f32_16x16x32_f16(ah[s][mf], bh[s][nf], acc[mf][nf], 0, 0, 0);
        __syncthreads();
        buf ^= 1;
    }

    #pragma unroll
    for (int mf = 0; mf < MF; ++mf)
        #pragma unroll
        for (int nf = 0; nf < NF; ++nf) {
            int col = n0 + wn * WN + nf * 16 + (lane & 15);
            if (col < N) {
                float bb = bias[col];
                #pragma unroll
                for (int r = 0; r < 4; ++r) {
                    int row = m0 + wm * WM + mf * 16 + ((lane >> 4) << 2) + r;
                    C[(size_t)row * ldc + col] = acc[mf][nf][r] + bb;
                }
            }
        }
}

// ------------- D3: LayerNorm rows -> fp16 (single)  ∥  w_kvb -> fp16 ----------
__global__ __launch_bounds__(256) void ln_mix(const float* __restrict__ h,
                                              const float* __restrict__ gamma,
                                              const float* __restrict__ beta,
                                              u16* __restrict__ hh,
                                              const float* __restrict__ w_kvb,
                                              u16* __restrict__ wkh) {
    const int bid = blockIdx.x;
    const int t   = threadIdx.x;
    if (bid >= BSZ) {                      // w_kvb conversion blocks
        long lq = (long)(bid - BSZ) * 256 + t;
        float4 v = (lq < QKVALID) ? ((const float4*)w_kvb)[lq]
                                  : make_float4(0.f, 0.f, 0.f, 0.f);
        ushort4 hh4;
        hh4.x = f2h(v.x); hh4.y = f2h(v.y); hh4.z = f2h(v.z); hh4.w = f2h(v.w);
        ((ushort4*)wkh)[lq] = hh4;
        return;
    }
    const int row = bid;
    const float* hr = h + (size_t)row * HID;

    float4 v = *(const float4*)(hr + t * 4);
    float s  = v.x + v.y + v.z + v.w;
    float sq = v.x * v.x + v.y * v.y + v.z * v.z + v.w * v.w;

    #pragma unroll
    for (int off = 1; off < 64; off <<= 1) {
        s  += __shfl_xor(s, off);
        sq += __shfl_xor(sq, off);
    }
    __shared__ float red[8];
    const int wid = t >> 6;
    if ((t & 63) == 0) { red[wid] = s; red[4 + wid] = sq; }
    __syncthreads();
    s  = red[0] + red[1] + red[2] + red[3];
    sq = red[4] + red[5] + red[6] + red[7];

    const float mu  = s * (1.f / HID);
    const float var = sq * (1.f / HID) - mu * mu;
    const float inv = rsqrtf(var + LN_EPS);

    float4 g  = *(const float4*)(gamma + t * 4);
    float4 be = *(const float4*)(beta + t * 4);
    float o[4];
    o[0] = (v.x - mu) * inv * g.x + be.x;
    o[1] = (v.y - mu) * inv * g.y + be.y;
    o[2] = (v.z - mu) * inv * g.z + be.z;
    o[3] = (v.w - mu) * inv * g.w + be.w;

    ushort4 uh;
    uh.x = f2h(o[0]); uh.y = f2h(o[1]); uh.z = f2h(o[2]); uh.w = f2h(o[3]);
    ((ushort4*)(hh + (size_t)row * HID))[t] = uh;
}

// ------------- D5: tail, 2-pair pipelined wave --------------------------------
// Each wave handles 2 adjacent (b,head) pairs. Pair-1's 16 W loads are issued
// right after pair-0's FMA chain (wv registers dead), so pair-0's softmax and
// 16 KB store stream overlap pair-1's load latency.
__global__ __launch_bounds__(256) void oja_tail(const float* __restrict__ out2,
                                                const float* __restrict__ W,
                                                float* __restrict__ dW) {
    const int lane = threadIdx.x & 63;
    const int wid  = threadIdx.x >> 6;
    const int pair0 = (blockIdx.x * 4 + wid) * 2;   // even pair
    const int b     = pair0 >> 4;
    const int head0 = pair0 & 15;

    const int g   = lane >> 4;
    const int c16 = lane & 15;

    const f32x4* wb0 = (const f32x4*)(W + (size_t)pair0 * (HD * HD));
    const f32x4* wb1 = wb0 + (HD * HD / 4);
    f32x4* ob0 = (f32x4*)(dW + (size_t)pair0 * (HD * HD));
    f32x4* ob1 = ob0 + (HD * HD / 4);
    const float* orow0 = out2 + (size_t)b * KVB + head0 * (2 * HD + 1);
    const float* orow1 = orow0 + (2 * HD + 1);

    // ---- pair 0: issue full W stream ----
    f32x4 wv[16];
    #pragma unroll
    for (int tt = 0; tt < 16; ++tt)
        wv[tt] = __builtin_nontemporal_load(wb0 + (4 * tt + g) * 16 + c16);

    // pair-0 out2 + transcendentals (hide under W latency)
    const float kin0   = orow0[lane];
    const float vful0  = tanhf(orow0[64 + lane]);
    float t30 = 0.f;
    if (lane == 0) t30 = orow0[128];
    const float lr0 = 1.f / (1.f + expf(-__shfl(t30, 0)));

    float rem0[4] = {0.f, 0.f, 0.f, 0.f};
    #pragma unroll
    for (int tt = 0; tt < 16; ++tt) {
        const float vsi = __shfl(vful0, 4 * tt + g);
        rem0[0] = fmaf(wv[tt][0], vsi, rem0[0]);
        rem0[1] = fmaf(wv[tt][1], vsi, rem0[1]);
        rem0[2] = fmaf(wv[tt][2], vsi, rem0[2]);
        rem0[3] = fmaf(wv[tt][3], vsi, rem0[3]);
    }

    // ---- pair 1: issue full W stream now (wv dead; overlaps pair-0 epilogue) ----
    f32x4 wu[16];
    #pragma unroll
    for (int tt = 0; tt < 16; ++tt)
        wu[tt] = __builtin_nontemporal_load(wb1 + (4 * tt + g) * 16 + c16);

    const float kin1  = orow1[lane];
    const float vful1 = tanhf(orow1[64 + lane]);
    float t31 = 0.f;
    if (lane == 0) t31 = orow1[128];
    const float lr1 = 1.f / (1.f + expf(-__shfl(t31, 0)));

    // ---- pair 0 softmax + store (overlaps pair-1 loads) ----
    #pragma unroll
    for (int q = 0; q < 4; ++q) {
        rem0[q] += __shfl_xor(rem0[q], 16);
        rem0[q] += __shfl_xor(rem0[q], 32);
    }
    float L0[4];
    #pragma unroll
    for (int q = 0; q < 4; ++q)
        L0[q] = __shfl(kin0, 4 * c16 + q) - rem0[q];
    float mx0 = fmaxf(fmaxf(L0[0], L0[1]), fmaxf(L0[2], L0[3]));
    #pragma unroll
    for (int off = 1; off < 16; off <<= 1)
        mx0 = fmaxf(mx0, __shfl_xor(mx0, off));
    float e0[4], ss0 = 0.f;
    #pragma unroll
    for (int q = 0; q < 4; ++q) { e0[q] = expf(L0[q] - mx0); ss0 += e0[q]; }
    #pragma unroll
    for (int off = 1; off < 16; off <<= 1)
        ss0 += __shfl_xor(ss0, off);
    const float sc0 = lr0 / ss0;
    float ks0[4];
    #pragma unroll
    for (int q = 0; q < 4; ++q) ks0[q] = e0[q] * sc0;

    #pragma unroll
    for (int tt = 0; tt < 16; ++tt) {
        const int i = 4 * tt + g;
        const float vsi = __shfl(vful0, i);
        f32x4 o;
        o[0] = vsi * ks0[0]; o[1] = vsi * ks0[1];
        o[2] = vsi * ks0[2]; o[3] = vsi * ks0[3];
        __builtin_nontemporal_store(o, ob0 + i * 16 + c16);
    }

    // ---- pair 1 FMA + softmax + store ----
    float rem1[4] = {0.f, 0.f, 0.f, 0.f};
    #pragma unroll
    for (int tt = 0; tt < 16; ++tt) {
        const float vsi = __shfl(vful1, 4 * tt + g);
        rem1[0] = fmaf(wu[tt][0], vsi, rem1[0]);
        rem1[1] = fmaf(wu[tt][1], vsi, rem1[1]);
        rem1[2] = fmaf(wu[tt][2], vsi, rem1[2]);
        rem1[3] = fmaf(wu[tt][3], vsi, rem1[3]);
    }
    #pragma unroll
    for (int q = 0; q < 4; ++q) {
        rem1[q] += __shfl_xor(rem1[q], 16);
        rem1[q] += __shfl_xor(rem1[q], 32);
    }
    float L1[4];
    #pragma unroll
    for (int q = 0; q < 4; ++q)
        L1[q] = __shfl(kin1, 4 * c16 + q) - rem1[q];
    float mx1 = fmaxf(fmaxf(L1[0], L1[1]), fmaxf(L1[2], L1[3]));
    #pragma unroll
    for (int off = 1; off < 16; off <<= 1)
        mx1 = fmaxf(mx1, __shfl_xor(mx1, off));
    float e1[4], ss1 = 0.f;
    #pragma unroll
    for (int q = 0; q < 4; ++q) { e1[q] = expf(L1[q] - mx1); ss1 += e1[q]; }
    #pragma unroll
    for (int off = 1; off < 16; off <<= 1)
        ss1 += __shfl_xor(ss1, off);
    const float sc1 = lr1 / ss1;
    float ks1[4];
    #pragma unroll
    for (int q = 0; q < 4; ++q) ks1[q] = e1[q] * sc1;

    #pragma unroll
    for (int tt = 0; tt < 16; ++tt) {
        const int i = 4 * tt + g;
        const float vsi = __shfl(vful1, i);
        f32x4 o;
        o[0] = vsi * ks1[0]; o[1] = vsi * ks1[1];
        o[2] = vsi * ks1[2]; o[3] = vsi * ks1[3];
        __builtin_nontemporal_store(o, ob1 + i * 16 + c16);
    }
}

extern "C" void kernel_launch(void* const* d_in, const int* in_sizes, int n_in,
                              void* d_out, int out_size, void* d_ws, size_t ws_size,
                              hipStream_t stream) {
    const float* x     = (const float*)d_in[0];
    const float* W     = (const float*)d_in[1];
    const float* w_in  = (const float*)d_in[2];
    const float* b_in  = (const float*)d_in[3];
    const float* gamma = (const float*)d_in[4];
    const float* beta  = (const float*)d_in[5];
    const float* w_kvb = (const float*)d_in[6];
    const float* b_kvb = (const float*)d_in[7];
    float* dW = (float*)d_out;

    char* p = (char*)d_ws;
    auto carve = [&](size_t bytes) { char* r = p; p += (bytes + 255) & ~(size_t)255; return r; };
    float* h    = (float*)carve((size_t)BSZ * HID * 4);
    float* out2 = (float*)carve((size_t)BSZ * KVB * 4);
    u16* xh  = (u16*)carve((size_t)BSZ * IN_CH * 2);
    u16* xl  = (u16*)carve((size_t)BSZ * IN_CH * 2);
    u16* wih = (u16*)carve((size_t)HID * IN_CH * 2);
    u16* hh  = (u16*)carve((size_t)BSZ * HID * 2);
    u16* wkh = (u16*)carve((size_t)NPAD * HID * 2);

    // D1: x split + w_in convert  (1024 blocks)
    cvt_xw<<<(QX + QW) / 256, 256, 0, stream>>>(x, w_in, xh, xl, wih);

    // D2: h = x @ w_in^T + b_in   (M=1024, N=1024, K=512), A-split fp16
    gemm_f16s<32, 64, IN_CH><<<dim3(HID / 64, BSZ / 32), 256, 0, stream>>>(
        xh, xl, wih, b_in, h, HID, HID);

    // D3: LayerNorm -> fp16 (1024 blocks)  ∥  w_kvb fp16 convert (2112 blocks)
    ln_mix<<<BSZ + QK / 256, 256, 0, stream>>>(h, gamma, beta, hh, w_kvb, wkh);

    // D4: out2 = h @ w_kvb^T + b_kvb  (single fp16; 528 blocks, XCD swizzle)
    gemm_f16x<64, 64, HID><<<(NPAD / 64) * (BSZ / 64), 256, 0, stream>>>(
        hh, wkh, b_kvb, out2, KVB, KVB);

    // D5: tail (2-pair pipelined waves; 2048 blocks)
    oja_tail<<<(BSZ * NH) / 8, 256, 0, stream>>>(out2, W, dW);
}

// Round 12
// 128.800 us; speedup vs baseline: 1.0057x; 1.0057x over previous
//
#include <hip/hip_runtime.h>
#include <hip/hip_bf16.h>
#include <math.h>

#define IN_CH 512
#define HID   1024
#define NH    16
#define HD    64
#define BSZ   1024
#define KVB   2064
#define NPAD  2112
#define LN_EPS 1e-5f

typedef _Float16 f16x8 __attribute__((ext_vector_type(8)));
typedef float f32x4  __attribute__((ext_vector_type(4)));
typedef unsigned short u16;

__device__ inline u16 f2h(float f) {
    _Float16 h = (_Float16)f;
    return __builtin_bit_cast(u16, h);
}

__device__ inline void gload16(const void* g, void* l) {
    __builtin_amdgcn_global_load_lds(
        (const __attribute__((address_space(1))) unsigned int*)g,
        (__attribute__((address_space(3))) unsigned int*)l, 16, 0, 0);
}

#define QX (BSZ * IN_CH / 4)              // 131072
#define QW (HID * IN_CH / 4)              // 131072
#define QK (NPAD * HID / 4)               // 540672
#define QKVALID (KVB * HID / 4)           // 528384

// ------------- D1: x -> fp16; w_in -> fp16 ------------------------------------
__global__ __launch_bounds__(256) void cvt_xw(const float* __restrict__ x,
                                              const float* __restrict__ w_in,
                                              u16* __restrict__ xh,
                                              u16* __restrict__ wih) {
    long q = (long)blockIdx.x * 256 + threadIdx.x;
    const float* src; u16* dst; long lq;
    if (q < QX) { src = x;    dst = xh;  lq = q; }
    else        { src = w_in; dst = wih; lq = q - QX; }
    float4 v = ((const float4*)src)[lq];
    ushort4 hh4;
    hh4.x = f2h(v.x); hh4.y = f2h(v.y); hh4.z = f2h(v.z); hh4.w = f2h(v.w);
    ((ushort4*)dst)[lq] = hh4;
}

// ------------- single-fp16 GEMM template (BK=64, XOR swizzle, opt XCD remap) --
// C = A @ B^T + bias.  256 thr = 4 waves (2x2).
template<int BM, int BN, int KK, bool SWZ>
__global__ __launch_bounds__(256) void gemm_f16x(const u16* __restrict__ Ah_g,
                                                 const u16* __restrict__ Bh_g,
                                                 const float* __restrict__ bias,
                                                 float* __restrict__ C,
                                                 int N, int ldc) {
    constexpr int WM = BM / 2, WN = BN / 2, MF = WM / 16, NF = WN / 16;
    constexpr int UA = BM / 8;
    constexpr int U  = UA + BN / 8;
    __shared__ __align__(16) u16 Ah[2][BM][64];
    __shared__ __align__(16) u16 Bh[2][BN][64];

    const int t = threadIdx.x, lane = t & 63, wid = t >> 6;
    const int wm = wid >> 1, wn = wid & 1;

    int mt, nt;
    if (SWZ) {
        // XCD-chunked bijective remap (grid % 8 == 0)
        const int bid = blockIdx.x, nwg = gridDim.x;
        const int w = (bid & 7) * (nwg >> 3) + (bid >> 3);
        mt = w & (BSZ / BM - 1);
        nt = w / (BSZ / BM);
    } else {
        nt = blockIdx.x; mt = blockIdx.y;
    }
    const int m0 = mt * BM, n0 = nt * BN;

    const int seg = (lane & 7) ^ (lane >> 3);
    const int r8  = lane >> 3;

    f32x4 acc[MF][NF] = {};

    auto stage = [&](int buf, int k0) {
        #pragma unroll
        for (int it = 0; it < U / 4; ++it) {
            int u = it * 4 + wid;
            if (u < UA) {
                int row = u * 8 + r8;
                gload16(Ah_g + (size_t)(m0 + row) * KK + k0 + seg * 8,
                        &Ah[buf][u * 8][0]);
            } else {
                int bu = u - UA;
                int row = bu * 8 + r8;
                gload16(Bh_g + (size_t)(n0 + row) * KK + k0 + seg * 8,
                        &Bh[buf][bu * 8][0]);
            }
        }
    };

    constexpr int KT = KK / 64;
    stage(0, 0);
    __syncthreads();
    int buf = 0;
    for (int kt = 0; kt < KT; ++kt) {
        if (kt + 1 < KT) stage(buf ^ 1, (kt + 1) * 64);

        f16x8 ah[2][MF], bh[2][NF];
        #pragma unroll
        for (int s = 0; s < 2; ++s) {
            #pragma unroll
            for (int mf = 0; mf < MF; ++mf) {
                int r = wm * WM + mf * 16 + (lane & 15);
                int pc = ((s << 2) | (lane >> 4)) ^ (r & 7);
                ah[s][mf] = *(const f16x8*)&Ah[buf][r][pc * 8];
            }
            #pragma unroll
            for (int nf = 0; nf < NF; ++nf) {
                int r = wn * WN + nf * 16 + (lane & 15);
                int pc = ((s << 2) | (lane >> 4)) ^ (r & 7);
                bh[s][nf] = *(const f16x8*)&Bh[buf][r][pc * 8];
            }
        }
        #pragma unroll
        for (int s = 0; s < 2; ++s)
            #pragma unroll
            for (int mf = 0; mf < MF; ++mf)
                #pragma unroll
                for (int nf = 0; nf < NF; ++nf)
                    acc[mf][nf] = __builtin_amdgcn_mfma_f32_16x16x32_f16(ah[s][mf], bh[s][nf], acc[mf][nf], 0, 0, 0);
        __syncthreads();
        buf ^= 1;
    }

    #pragma unroll
    for (int mf = 0; mf < MF; ++mf)
        #pragma unroll
        for (int nf = 0; nf < NF; ++nf) {
            int col = n0 + wn * WN + nf * 16 + (lane & 15);
            if (col < N) {
                float bb = bias[col];
                #pragma unroll
                for (int r = 0; r < 4; ++r) {
                    int row = m0 + wm * WM + mf * 16 + ((lane >> 4) << 2) + r;
                    C[(size_t)row * ldc + col] = acc[mf][nf][r] + bb;
                }
            }
        }
}

// ------------- D3: LayerNorm rows -> fp16 (single)  ∥  w_kvb -> fp16 ----------
__global__ __launch_bounds__(256) void ln_mix(const float* __restrict__ h,
                                              const float* __restrict__ gamma,
                                              const float* __restrict__ beta,
                                              u16* __restrict__ hh,
                                              const float* __restrict__ w_kvb,
                                              u16* __restrict__ wkh) {
    const int bid = blockIdx.x;
    const int t   = threadIdx.x;
    if (bid >= BSZ) {                      // w_kvb conversion blocks
        long lq = (long)(bid - BSZ) * 256 + t;
        float4 v = (lq < QKVALID) ? ((const float4*)w_kvb)[lq]
                                  : make_float4(0.f, 0.f, 0.f, 0.f);
        ushort4 hh4;
        hh4.x = f2h(v.x); hh4.y = f2h(v.y); hh4.z = f2h(v.z); hh4.w = f2h(v.w);
        ((ushort4*)wkh)[lq] = hh4;
        return;
    }
    const int row = bid;
    const float* hr = h + (size_t)row * HID;

    float4 v = *(const float4*)(hr + t * 4);
    float s  = v.x + v.y + v.z + v.w;
    float sq = v.x * v.x + v.y * v.y + v.z * v.z + v.w * v.w;

    #pragma unroll
    for (int off = 1; off < 64; off <<= 1) {
        s  += __shfl_xor(s, off);
        sq += __shfl_xor(sq, off);
    }
    __shared__ float red[8];
    const int wid = t >> 6;
    if ((t & 63) == 0) { red[wid] = s; red[4 + wid] = sq; }
    __syncthreads();
    s  = red[0] + red[1] + red[2] + red[3];
    sq = red[4] + red[5] + red[6] + red[7];

    const float mu  = s * (1.f / HID);
    const float var = sq * (1.f / HID) - mu * mu;
    const float inv = rsqrtf(var + LN_EPS);

    float4 g  = *(const float4*)(gamma + t * 4);
    float4 be = *(const float4*)(beta + t * 4);
    float o[4];
    o[0] = (v.x - mu) * inv * g.x + be.x;
    o[1] = (v.y - mu) * inv * g.y + be.y;
    o[2] = (v.z - mu) * inv * g.z + be.z;
    o[3] = (v.w - mu) * inv * g.w + be.w;

    ushort4 uh;
    uh.x = f2h(o[0]); uh.y = f2h(o[1]); uh.z = f2h(o[2]); uh.w = f2h(o[3]);
    ((ushort4*)(hh + (size_t)row * HID))[t] = uh;
}

// ------------- D5: tail, one wave per (b, head), 16 batched W loads -----------
__global__ __launch_bounds__(256) void oja_tail(const float* __restrict__ out2,
                                                const float* __restrict__ W,
                                                float* __restrict__ dW) {
    const int lane = threadIdx.x & 63;
    const int wid  = threadIdx.x >> 6;
    const int pair = blockIdx.x * 4 + wid;      // b*16 + head
    const int b    = pair >> 4;
    const int head = pair & 15;

    const int g   = lane >> 4;
    const int c16 = lane & 15;

    // issue the full W block stream first (max MLP)
    const f32x4* wbh = (const f32x4*)(W + (size_t)pair * (HD * HD));
    f32x4 wv[16];
    #pragma unroll
    for (int tt = 0; tt < 16; ++tt)
        wv[tt] = __builtin_nontemporal_load(wbh + (4 * tt + g) * 16 + c16);

    // out2 slice + transcendentals (hidden under W latency)
    const float* orow = out2 + (size_t)b * KVB + head * (2 * HD + 1);
    const float kin   = orow[lane];
    const float vfull = tanhf(orow[64 + lane]);
    float t3 = 0.f;
    if (lane == 0) t3 = orow[128];
    const float lrl = __shfl(t3, 0);
    const float lr  = 1.f / (1.f + expf(-lrl));

    float rem[4] = {0.f, 0.f, 0.f, 0.f};
    #pragma unroll
    for (int tt = 0; tt < 16; ++tt) {
        const float vsi = __shfl(vfull, 4 * tt + g);
        rem[0] = fmaf(wv[tt][0], vsi, rem[0]);
        rem[1] = fmaf(wv[tt][1], vsi, rem[1]);
        rem[2] = fmaf(wv[tt][2], vsi, rem[2]);
        rem[3] = fmaf(wv[tt][3], vsi, rem[3]);
    }
    #pragma unroll
    for (int q = 0; q < 4; ++q) {
        rem[q] += __shfl_xor(rem[q], 16);
        rem[q] += __shfl_xor(rem[q], 32);
    }

    float L[4];
    #pragma unroll
    for (int q = 0; q < 4; ++q)
        L[q] = __shfl(kin, 4 * c16 + q) - rem[q];

    float mx = fmaxf(fmaxf(L[0], L[1]), fmaxf(L[2], L[3]));
    #pragma unroll
    for (int off = 1; off < 16; off <<= 1)
        mx = fmaxf(mx, __shfl_xor(mx, off));

    float e[4], ssum = 0.f;
    #pragma unroll
    for (int q = 0; q < 4; ++q) { e[q] = expf(L[q] - mx); ssum += e[q]; }
    #pragma unroll
    for (int off = 1; off < 16; off <<= 1)
        ssum += __shfl_xor(ssum, off);

    const float scale = lr / ssum;
    float ks[4];
    #pragma unroll
    for (int q = 0; q < 4; ++q) ks[q] = e[q] * scale;

    f32x4* obh = (f32x4*)(dW + (size_t)pair * (HD * HD));
    #pragma unroll
    for (int tt = 0; tt < 16; ++tt) {
        const int i = 4 * tt + g;
        const float vsi = __shfl(vfull, i);
        f32x4 o;
        o[0] = vsi * ks[0]; o[1] = vsi * ks[1];
        o[2] = vsi * ks[2]; o[3] = vsi * ks[3];
        __builtin_nontemporal_store(o, obh + i * 16 + c16);
    }
}

extern "C" void kernel_launch(void* const* d_in, const int* in_sizes, int n_in,
                              void* d_out, int out_size, void* d_ws, size_t ws_size,
                              hipStream_t stream) {
    const float* x     = (const float*)d_in[0];
    const float* W     = (const float*)d_in[1];
    const float* w_in  = (const float*)d_in[2];
    const float* b_in  = (const float*)d_in[3];
    const float* gamma = (const float*)d_in[4];
    const float* beta  = (const float*)d_in[5];
    const float* w_kvb = (const float*)d_in[6];
    const float* b_kvb = (const float*)d_in[7];
    float* dW = (float*)d_out;

    char* p = (char*)d_ws;
    auto carve = [&](size_t bytes) { char* r = p; p += (bytes + 255) & ~(size_t)255; return r; };
    float* h    = (float*)carve((size_t)BSZ * HID * 4);
    float* out2 = (float*)carve((size_t)BSZ * KVB * 4);
    u16* xh  = (u16*)carve((size_t)BSZ * IN_CH * 2);
    u16* wih = (u16*)carve((size_t)HID * IN_CH * 2);
    u16* hh  = (u16*)carve((size_t)BSZ * HID * 2);
    u16* wkh = (u16*)carve((size_t)NPAD * HID * 2);

    // D1: x + w_in -> fp16  (1024 blocks)
    cvt_xw<<<(QX + QW) / 256, 256, 0, stream>>>(x, w_in, xh, wih);

    // D2: h = x @ w_in^T + b_in   (M=1024, N=1024, K=512), single fp16
    gemm_f16x<32, 64, IN_CH, false><<<dim3(HID / 64, BSZ / 32), 256, 0, stream>>>(
        xh, wih, b_in, h, HID, HID);

    // D3: LayerNorm -> fp16 (1024 blocks)  ∥  w_kvb fp16 convert (2112 blocks)
    ln_mix<<<BSZ + QK / 256, 256, 0, stream>>>(h, gamma, beta, hh, w_kvb, wkh);

    // D4: out2 = h @ w_kvb^T + b_kvb  (single fp16; 528 blocks, XCD swizzle)
    gemm_f16x<64, 64, HID, true><<<(NPAD / 64) * (BSZ / 64), 256, 0, stream>>>(
        hh, wkh, b_kvb, out2, KVB, KVB);

    // D5: tail (register-batched W stream)
    oja_tail<<<(BSZ * NH) / 4, 256, 0, stream>>>(out2, W, dW);
}

// Round 13
// 120.858 us; speedup vs baseline: 1.0718x; 1.0657x over previous
//
#include <hip/hip_runtime.h>
#include <hip/hip_bf16.h>
#include <math.h>

#define IN_CH 512
#define HID   1024
#define NH    16
#define HD    64
#define BSZ   1024
#define KVB   2064
#define NPAD  2112
#define LN_EPS 1e-5f

typedef _Float16 f16x8 __attribute__((ext_vector_type(8)));
typedef float f32x4  __attribute__((ext_vector_type(4)));
typedef unsigned short u16;

__device__ inline u16 f2h(float f) {
    _Float16 h = (_Float16)f;
    return __builtin_bit_cast(u16, h);
}

__device__ inline void gload16(const void* g, void* l) {
    __builtin_amdgcn_global_load_lds(
        (const __attribute__((address_space(1))) unsigned int*)g,
        (__attribute__((address_space(3))) unsigned int*)l, 16, 0, 0);
}

#define QX (BSZ * IN_CH / 4)              // 131072
#define QW (HID * IN_CH / 4)              // 131072
#define QK (NPAD * HID / 4)               // 540672
#define QKVALID (KVB * HID / 4)           // 528384

// ------------- D1: x -> fp16; w_in -> fp16 ------------------------------------
__global__ __launch_bounds__(256) void cvt_xw(const float* __restrict__ x,
                                              const float* __restrict__ w_in,
                                              u16* __restrict__ xh,
                                              u16* __restrict__ wih) {
    long q = (long)blockIdx.x * 256 + threadIdx.x;
    const float* src; u16* dst; long lq;
    if (q < QX) { src = x;    dst = xh;  lq = q; }
    else        { src = w_in; dst = wih; lq = q - QX; }
    float4 v = ((const float4*)src)[lq];
    ushort4 hh4;
    hh4.x = f2h(v.x); hh4.y = f2h(v.y); hh4.z = f2h(v.z); hh4.w = f2h(v.w);
    ((ushort4*)dst)[lq] = hh4;
}

// ------------- single-fp16 GEMM template (BK=64, XOR swizzle, opt XCD remap) --
// C = A @ B^T + bias.  256 thr = 4 waves (2x2).
template<int BM, int BN, int KK, bool SWZ>
__global__ __launch_bounds__(256) void gemm_f16x(const u16* __restrict__ Ah_g,
                                                 const u16* __restrict__ Bh_g,
                                                 const float* __restrict__ bias,
                                                 float* __restrict__ C,
                                                 int N, int ldc) {
    constexpr int WM = BM / 2, WN = BN / 2, MF = WM / 16, NF = WN / 16;
    constexpr int UA = BM / 8;
    constexpr int U  = UA + BN / 8;
    __shared__ __align__(16) u16 Ah[2][BM][64];
    __shared__ __align__(16) u16 Bh[2][BN][64];

    const int t = threadIdx.x, lane = t & 63, wid = t >> 6;
    const int wm = wid >> 1, wn = wid & 1;

    int mt, nt;
    if (SWZ) {
        // XCD-chunked bijective remap (grid % 8 == 0)
        const int bid = blockIdx.x, nwg = gridDim.x;
        const int w = (bid & 7) * (nwg >> 3) + (bid >> 3);
        mt = w & (BSZ / BM - 1);
        nt = w / (BSZ / BM);
    } else {
        nt = blockIdx.x; mt = blockIdx.y;
    }
    const int m0 = mt * BM, n0 = nt * BN;

    const int seg = (lane & 7) ^ (lane >> 3);
    const int r8  = lane >> 3;

    f32x4 acc[MF][NF] = {};

    auto stage = [&](int buf, int k0) {
        #pragma unroll
        for (int it = 0; it < U / 4; ++it) {
            int u = it * 4 + wid;
            if (u < UA) {
                int row = u * 8 + r8;
                gload16(Ah_g + (size_t)(m0 + row) * KK + k0 + seg * 8,
                        &Ah[buf][u * 8][0]);
            } else {
                int bu = u - UA;
                int row = bu * 8 + r8;
                gload16(Bh_g + (size_t)(n0 + row) * KK + k0 + seg * 8,
                        &Bh[buf][bu * 8][0]);
            }
        }
    };

    constexpr int KT = KK / 64;
    stage(0, 0);
    __syncthreads();
    int buf = 0;
    for (int kt = 0; kt < KT; ++kt) {
        if (kt + 1 < KT) stage(buf ^ 1, (kt + 1) * 64);

        f16x8 ah[2][MF], bh[2][NF];
        #pragma unroll
        for (int s = 0; s < 2; ++s) {
            #pragma unroll
            for (int mf = 0; mf < MF; ++mf) {
                int r = wm * WM + mf * 16 + (lane & 15);
                int pc = ((s << 2) | (lane >> 4)) ^ (r & 7);
                ah[s][mf] = *(const f16x8*)&Ah[buf][r][pc * 8];
            }
            #pragma unroll
            for (int nf = 0; nf < NF; ++nf) {
                int r = wn * WN + nf * 16 + (lane & 15);
                int pc = ((s << 2) | (lane >> 4)) ^ (r & 7);
                bh[s][nf] = *(const f16x8*)&Bh[buf][r][pc * 8];
            }
        }
        #pragma unroll
        for (int s = 0; s < 2; ++s)
            #pragma unroll
            for (int mf = 0; mf < MF; ++mf)
                #pragma unroll
                for (int nf = 0; nf < NF; ++nf)
                    acc[mf][nf] = __builtin_amdgcn_mfma_f32_16x16x32_f16(ah[s][mf], bh[s][nf], acc[mf][nf], 0, 0, 0);
        __syncthreads();
        buf ^= 1;
    }

    #pragma unroll
    for (int mf = 0; mf < MF; ++mf)
        #pragma unroll
        for (int nf = 0; nf < NF; ++nf) {
            int col = n0 + wn * WN + nf * 16 + (lane & 15);
            if (col < N) {
                float bb = bias[col];
                #pragma unroll
                for (int r = 0; r < 4; ++r) {
                    int row = m0 + wm * WM + mf * 16 + ((lane >> 4) << 2) + r;
                    C[(size_t)row * ldc + col] = acc[mf][nf][r] + bb;
                }
            }
        }
}

// ------------- D3: LayerNorm rows -> fp16 (single)  ∥  w_kvb -> fp16 ----------
__global__ __launch_bounds__(256) void ln_mix(const float* __restrict__ h,
                                              const float* __restrict__ gamma,
                                              const float* __restrict__ beta,
                                              u16* __restrict__ hh,
                                              const float* __restrict__ w_kvb,
                                              u16* __restrict__ wkh) {
    const int bid = blockIdx.x;
    const int t   = threadIdx.x;
    if (bid >= BSZ) {                      // w_kvb conversion blocks
        long lq = (long)(bid - BSZ) * 256 + t;
        float4 v = (lq < QKVALID) ? ((const float4*)w_kvb)[lq]
                                  : make_float4(0.f, 0.f, 0.f, 0.f);
        ushort4 hh4;
        hh4.x = f2h(v.x); hh4.y = f2h(v.y); hh4.z = f2h(v.z); hh4.w = f2h(v.w);
        ((ushort4*)wkh)[lq] = hh4;
        return;
    }
    const int row = bid;
    const float* hr = h + (size_t)row * HID;

    float4 v = *(const float4*)(hr + t * 4);
    float s  = v.x + v.y + v.z + v.w;
    float sq = v.x * v.x + v.y * v.y + v.z * v.z + v.w * v.w;

    #pragma unroll
    for (int off = 1; off < 64; off <<= 1) {
        s  += __shfl_xor(s, off);
        sq += __shfl_xor(sq, off);
    }
    __shared__ float red[8];
    const int wid = t >> 6;
    if ((t & 63) == 0) { red[wid] = s; red[4 + wid] = sq; }
    __syncthreads();
    s  = red[0] + red[1] + red[2] + red[3];
    sq = red[4] + red[5] + red[6] + red[7];

    const float mu  = s * (1.f / HID);
    const float var = sq * (1.f / HID) - mu * mu;
    const float inv = rsqrtf(var + LN_EPS);

    float4 g  = *(const float4*)(gamma + t * 4);
    float4 be = *(const float4*)(beta + t * 4);
    float o[4];
    o[0] = (v.x - mu) * inv * g.x + be.x;
    o[1] = (v.y - mu) * inv * g.y + be.y;
    o[2] = (v.z - mu) * inv * g.z + be.z;
    o[3] = (v.w - mu) * inv * g.w + be.w;

    ushort4 uh;
    uh.x = f2h(o[0]); uh.y = f2h(o[1]); uh.z = f2h(o[2]); uh.w = f2h(o[3]);
    ((ushort4*)(hh + (size_t)row * HID))[t] = uh;
}

// ------------- D5: tail, one wave per (b, head), 16 batched W loads -----------
// Loads stay nontemporal (read-once); stores are NORMAL (L2 write-combine path,
// same as the 6.9 TB/s fill kernel) — single-variable test vs round 12.
__global__ __launch_bounds__(256) void oja_tail(const float* __restrict__ out2,
                                                const float* __restrict__ W,
                                                float* __restrict__ dW) {
    const int lane = threadIdx.x & 63;
    const int wid  = threadIdx.x >> 6;
    const int pair = blockIdx.x * 4 + wid;      // b*16 + head
    const int b    = pair >> 4;
    const int head = pair & 15;

    const int g   = lane >> 4;
    const int c16 = lane & 15;

    // issue the full W block stream first (max MLP)
    const f32x4* wbh = (const f32x4*)(W + (size_t)pair * (HD * HD));
    f32x4 wv[16];
    #pragma unroll
    for (int tt = 0; tt < 16; ++tt)
        wv[tt] = __builtin_nontemporal_load(wbh + (4 * tt + g) * 16 + c16);

    // out2 slice + transcendentals (hidden under W latency)
    const float* orow = out2 + (size_t)b * KVB + head * (2 * HD + 1);
    const float kin   = orow[lane];
    const float vfull = tanhf(orow[64 + lane]);
    float t3 = 0.f;
    if (lane == 0) t3 = orow[128];
    const float lrl = __shfl(t3, 0);
    const float lr  = 1.f / (1.f + expf(-lrl));

    float rem[4] = {0.f, 0.f, 0.f, 0.f};
    #pragma unroll
    for (int tt = 0; tt < 16; ++tt) {
        const float vsi = __shfl(vfull, 4 * tt + g);
        rem[0] = fmaf(wv[tt][0], vsi, rem[0]);
        rem[1] = fmaf(wv[tt][1], vsi, rem[1]);
        rem[2] = fmaf(wv[tt][2], vsi, rem[2]);
        rem[3] = fmaf(wv[tt][3], vsi, rem[3]);
    }
    #pragma unroll
    for (int q = 0; q < 4; ++q) {
        rem[q] += __shfl_xor(rem[q], 16);
        rem[q] += __shfl_xor(rem[q], 32);
    }

    float L[4];
    #pragma unroll
    for (int q = 0; q < 4; ++q)
        L[q] = __shfl(kin, 4 * c16 + q) - rem[q];

    float mx = fmaxf(fmaxf(L[0], L[1]), fmaxf(L[2], L[3]));
    #pragma unroll
    for (int off = 1; off < 16; off <<= 1)
        mx = fmaxf(mx, __shfl_xor(mx, off));

    float e[4], ssum = 0.f;
    #pragma unroll
    for (int q = 0; q < 4; ++q) { e[q] = expf(L[q] - mx); ssum += e[q]; }
    #pragma unroll
    for (int off = 1; off < 16; off <<= 1)
        ssum += __shfl_xor(ssum, off);

    const float scale = lr / ssum;
    float ks[4];
    #pragma unroll
    for (int q = 0; q < 4; ++q) ks[q] = e[q] * scale;

    f32x4* obh = (f32x4*)(dW + (size_t)pair * (HD * HD));
    #pragma unroll
    for (int tt = 0; tt < 16; ++tt) {
        const int i = 4 * tt + g;
        const float vsi = __shfl(vfull, i);
        f32x4 o;
        o[0] = vsi * ks[0]; o[1] = vsi * ks[1];
        o[2] = vsi * ks[2]; o[3] = vsi * ks[3];
        obh[i * 16 + c16] = o;               // normal store (L2 path)
    }
}

extern "C" void kernel_launch(void* const* d_in, const int* in_sizes, int n_in,
                              void* d_out, int out_size, void* d_ws, size_t ws_size,
                              hipStream_t stream) {
    const float* x     = (const float*)d_in[0];
    const float* W     = (const float*)d_in[1];
    const float* w_in  = (const float*)d_in[2];
    const float* b_in  = (const float*)d_in[3];
    const float* gamma = (const float*)d_in[4];
    const float* beta  = (const float*)d_in[5];
    const float* w_kvb = (const float*)d_in[6];
    const float* b_kvb = (const float*)d_in[7];
    float* dW = (float*)d_out;

    char* p = (char*)d_ws;
    auto carve = [&](size_t bytes) { char* r = p; p += (bytes + 255) & ~(size_t)255; return r; };
    float* h    = (float*)carve((size_t)BSZ * HID * 4);
    float* out2 = (float*)carve((size_t)BSZ * KVB * 4);
    u16* xh  = (u16*)carve((size_t)BSZ * IN_CH * 2);
    u16* wih = (u16*)carve((size_t)HID * IN_CH * 2);
    u16* hh  = (u16*)carve((size_t)BSZ * HID * 2);
    u16* wkh = (u16*)carve((size_t)NPAD * HID * 2);

    // D1: x + w_in -> fp16  (1024 blocks)
    cvt_xw<<<(QX + QW) / 256, 256, 0, stream>>>(x, w_in, xh, wih);

    // D2: h = x @ w_in^T + b_in   (M=1024, N=1024, K=512), single fp16
    gemm_f16x<32, 64, IN_CH, false><<<dim3(HID / 64, BSZ / 32), 256, 0, stream>>>(
        xh, wih, b_in, h, HID, HID);

    // D3: LayerNorm -> fp16 (1024 blocks)  ∥  w_kvb fp16 convert (2112 blocks)
    ln_mix<<<BSZ + QK / 256, 256, 0, stream>>>(h, gamma, beta, hh, w_kvb, wkh);

    // D4: out2 = h @ w_kvb^T + b_kvb  (single fp16; 528 blocks, XCD swizzle)
    gemm_f16x<64, 64, HID, true><<<(NPAD / 64) * (BSZ / 64), 256, 0, stream>>>(
        hh, wkh, b_kvb, out2, KVB, KVB);

    // D5: tail (nt loads, normal stores)
    oja_tail<<<(BSZ * NH) / 4, 256, 0, stream>>>(out2, W, dW);
}